// Round 6
// baseline (447.033 us; speedup 1.0000x reference)
//
#include <hip/hip_runtime.h>
#include <hip/hip_fp16.h>
#include <math.h>

#define TB 8      // batch
#define TD 256    // d_model
#define TE 2048   // edges (sequence)
#define TH 8      // heads

typedef _Float16 h8 __attribute__((ext_vector_type(8)));
typedef float    f4 __attribute__((ext_vector_type(4)));

static __device__ __forceinline__ unsigned int packh2(float a, float b){
  __half2 h = __floats2half2_rn(a, b);
  return __builtin_bit_cast(unsigned int, h);
}

// ---------------- pack mask rows into bitmask [B*E][64 words]; self-detecting dtype ----------------
__global__ __launch_bounds__(256) void k_pack(const unsigned int* __restrict__ mraw,
                       unsigned int* __restrict__ packed, float* __restrict__ num){
  __shared__ int oks;
  const int t = threadIdx.x;
  if(t == 0) oks = 1;
  __syncthreads();
  int ok = 1;
  for(int i=t; i<4096; i+=256) if(mraw[i] > 1u) ok = 0;
  if(!ok) atomicAnd(&oks, 0);
  __syncthreads();
  const int isInt = oks;

  const int row = blockIdx.x*4 + (t >> 6);
  const int w = t & 63;
  const size_t base = (size_t)row*TE + (size_t)w*32;
  unsigned int bits = 0;
  if(isInt){
    const unsigned int* p = mraw + base;
    #pragma unroll
    for(int j=0;j<32;j++) bits |= (p[j] & 1u) << j;
  } else {
    const unsigned char* p = (const unsigned char*)mraw + base;
    #pragma unroll
    for(int j=0;j<32;j++) bits |= (unsigned int)(p[j] != 0) << j;
  }
  packed[(size_t)row*64 + w] = bits;
  if(blockIdx.x < 64) num[blockIdx.x*256 + t] = 0.f;   // zero per-edge numerator
}

// ---------------- denom[b][k] = sum_q mask[b][q][k] (from packed bits) ----------------
__global__ __launch_bounds__(256) void k_denom(const unsigned int* __restrict__ packed,
                        float* __restrict__ denom){
  const int b = blockIdx.z;
  const int k = blockIdx.x*256 + threadIdx.x;
  const int q0 = blockIdx.y*64;
  const unsigned int* p = packed + ((size_t)b*TE + q0)*64 + (k >> 5);
  const unsigned sh = k & 31;
  int cnt = 0;
  #pragma unroll 8
  for(int q=0;q<64;q++) cnt += (p[(size_t)q*64] >> sh) & 1u;
  atomicAdd(&denom[b*TE + k], (float)cnt);
}

// ---------------- weight transpose to fp16: qkvT [768][256] (Q|K|V cols), fcT [256][256] ----------------
__global__ __launch_bounds__(256) void k_wpack(
    const float* __restrict__ wqs, const float* __restrict__ wks,
    const float* __restrict__ wvs, const float* __restrict__ wfc,
    _Float16* __restrict__ qkvT, _Float16* __restrict__ fcT){
  const int n = blockIdx.x;          // 0..1023
  const int k = threadIdx.x;         // 0..255
  if(n < 256)      qkvT[(size_t)n*256 + k] = (_Float16)wqs[(size_t)k*256 + n];
  else if(n < 512) qkvT[(size_t)n*256 + k] = (_Float16)wks[(size_t)k*256 + (n-256)];
  else if(n < 768) qkvT[(size_t)n*256 + k] = (_Float16)wvs[(size_t)k*256 + (n-512)];
  else             fcT[(size_t)(n-768)*256 + k] = (_Float16)wfc[(size_t)k*256 + (n-768)];
}

// ---------------- transpose + LayerNorm + Q/K/V projections (MFMA) ----------------
// 16 edges/block, 4 waves. Wave w owns N-tiles {4w..4w+3} of each of Q, K, V.
// mfma(bf, af): bf lane c = W^T row (tile*16+c), af lane c = edge row; D[reg r][lane c]
// -> out[wcol tile*16+4g+r][edge c].
__global__ __launch_bounds__(256) void k_qkv(
    const float* __restrict__ x, const _Float16* __restrict__ qkvT,
    const float* __restrict__ gamma, const float* __restrict__ beta,
    _Float16* __restrict__ qh, _Float16* __restrict__ kh, _Float16* __restrict__ vt){
  __shared__ float xs[16][260];
  __shared__ __align__(16) _Float16 xh[16][264];
  __shared__ __align__(16) _Float16 qn[16][264];
  __shared__ float mu_s[16], rs_s[16];
  const int t = threadIdx.x;
  const int b = blockIdx.y;
  const int e0 = blockIdx.x*16;

  for(int i=t;i<16*256;i+=256){
    int el = i & 15, dd = i >> 4;
    xs[el][dd] = x[((size_t)(b*TD + dd))*TE + e0 + el];
  }
  __syncthreads();
  {
    int row = t >> 4, j = t & 15;
    float s1=0.f, s2=0.f;
    #pragma unroll
    for(int i=0;i<16;i++){ float v = xs[row][j*16+i]; s1 += v; s2 += v*v; }
    #pragma unroll
    for(int off=1; off<16; off<<=1){ s1 += __shfl_xor(s1, off); s2 += __shfl_xor(s2, off); }
    if(j==0){
      float m = s1 * (1.f/256.f);
      float var = s2 * (1.f/256.f) - m*m;
      mu_s[row] = m;
      rs_s[row] = rsqrtf(var + 1e-6f);
    }
  }
  __syncthreads();
  for(int i=t;i<16*256;i+=256){
    int r = i >> 8, dd = i & 255;
    float xv = xs[r][dd];
    xh[r][dd] = (_Float16)xv;
    qn[r][dd] = (_Float16)((xv - mu_s[r]) * rs_s[r] * gamma[dd] + beta[dd]);
  }
  __syncthreads();

  const int w = t >> 6, l = t & 63, g = l >> 4, c = l & 15;
  const f4 f4z = {0.f,0.f,0.f,0.f};
  const float sclq = 0.17677669529663687f * 1.44269504088896f;  // 1/sqrt(DK) * log2(e)
  h8 af[8];

  // ---- Q ----
  #pragma unroll
  for(int kk=0;kk<8;kk++) af[kk] = *(const h8*)&qn[c][kk*32 + g*8];
  #pragma unroll
  for(int i=0;i<4;i++){
    const int n0 = (4*w+i)*16;
    f4 acc = f4z;
    #pragma unroll
    for(int kk=0;kk<8;kk++){
      h8 bf = *(const h8*)(qkvT + (size_t)(n0 + c)*256 + kk*32 + g*8);
      acc = __builtin_amdgcn_mfma_f32_16x16x32_f16(bf, af[kk], acc, 0, 0, 0);
    }
    const int d0 = n0 + 4*g, hh = d0 >> 5, d2 = d0 & 31;
    uint2 ov;
    ov.x = packh2(acc[0]*sclq, acc[1]*sclq);
    ov.y = packh2(acc[2]*sclq, acc[3]*sclq);
    *(uint2*)&qh[((size_t)(b*TH+hh)*TE + e0 + c)*32 + d2] = ov;
  }
  // ---- K ----
  #pragma unroll
  for(int kk=0;kk<8;kk++) af[kk] = *(const h8*)&xh[c][kk*32 + g*8];
  #pragma unroll
  for(int i=0;i<4;i++){
    const int n0 = (4*w+i)*16;
    f4 acc = f4z;
    #pragma unroll
    for(int kk=0;kk<8;kk++){
      h8 bf = *(const h8*)(qkvT + (size_t)(256 + n0 + c)*256 + kk*32 + g*8);
      acc = __builtin_amdgcn_mfma_f32_16x16x32_f16(bf, af[kk], acc, 0, 0, 0);
    }
    const int d0 = n0 + 4*g, hh = d0 >> 5, d2 = d0 & 31;
    uint2 ov;
    ov.x = packh2(acc[0], acc[1]);
    ov.y = packh2(acc[2], acc[3]);
    *(uint2*)&kh[((size_t)(b*TH+hh)*TE + e0 + c)*32 + d2] = ov;
  }
  // ---- V (transposed + slot-permuted scatter: e' = 8*(c>>2) + 4*jj + (c&3)) ----
  const int jj = (e0 >> 4) & 1;
  const int ep = (e0 & ~31) + 8*(c>>2) + 4*jj + (c&3);
  #pragma unroll
  for(int i=0;i<4;i++){
    const int n0 = (4*w+i)*16;
    f4 acc = f4z;
    #pragma unroll
    for(int kk=0;kk<8;kk++){
      h8 bf = *(const h8*)(qkvT + (size_t)(512 + n0 + c)*256 + kk*32 + g*8);
      acc = __builtin_amdgcn_mfma_f32_16x16x32_f16(bf, af[kk], acc, 0, 0, 0);
    }
    #pragma unroll
    for(int r=0;r<4;r++){
      const int d = n0 + 4*g + r;
      vt[((size_t)(b*TH + (d>>5))*32 + (d&31))*TE + ep] = (_Float16)acc[r];
    }
  }
}

// ---------------- MFMA attention, swapped-operand, LDS-transposed full-line stores ----------------
// 1 block = 64 q-rows of one (b,h). 4 waves x 16 rows. Two passes over K.
// Mask words loaded per-kt direct from L2 (no LDS staging) -> 25.4 KB LDS, 6 blocks/CU.
__global__ __launch_bounds__(256) void k_attn(
    const _Float16* __restrict__ qh, const _Float16* __restrict__ kh, const _Float16* __restrict__ vt,
    const unsigned int* __restrict__ packed,
    float* __restrict__ attn, _Float16* __restrict__ owh, float* __restrict__ num){
  __shared__ float num_s[TE];
  __shared__ __align__(16) f4 S4[4][272];            // per-wave strip: 16 rows x 17 f4 (pad)

  const int t = threadIdx.x;
  int bid = blockIdx.x;
  bid = (bid & 7) * 256 + (bid >> 3);                // XCD-aware swizzle (2048 % 8 == 0)
  const int qt = bid & 31;
  const int bhid = bid >> 5;                         // 0..63
  const int h = bhid & 7, b = bhid >> 3;
  const size_t bh = (size_t)bhid * TE;
  const _Float16* Qg = qh + bh*32;
  const _Float16* Kg = kh + bh*32;
  const _Float16* Vg = vt + bh*32;                   // [32][TE], slot-permuted
  const int q0 = qt*64;

  const int wid = t >> 6, l = t & 63, g = l >> 4, c = l & 15;
  const int qr = wid*16 + c;
  const f4 f4z = {0.f, 0.f, 0.f, 0.f};

  for(int i=t;i<TE;i+=256) num_s[i] = 0.f;
  __syncthreads();

  // Q fragment (B-operand): lane holds Q-row (q0+qr), k-slice g*8 (log2e pre-folded)
  const h8 qf = *(const h8*)(Qg + (size_t)(q0 + qr)*32 + g*8);
  const uint2* mrow2 = (const uint2*)(packed + ((size_t)b*TE + q0 + qr)*64);

  // ---- pass 1: row sums of 2^s (no max-sub; masked -> 2^(-1e9)=0) ----
  float ll = 0.f;
  for(int kt=0; kt<32; ++kt){
    h8 kf[4];
    #pragma unroll
    for(int j=0;j<4;j++) kf[j] = *(const h8*)(Kg + (size_t)(kt*64 + j*16 + c)*32 + g*8);
    f4 s[4];
    #pragma unroll
    for(int j=0;j<4;j++) s[j] = __builtin_amdgcn_mfma_f32_16x16x32_f16(kf[j], qf, f4z, 0, 0, 0);
    const uint2 mw2 = mrow2[kt];
    #pragma unroll
    for(int j=0;j<4;j++){
      const unsigned mw = (j>>1) ? mw2.y : mw2.x;
      #pragma unroll
      for(int r=0;r<4;r++){
        float sv = ((mw >> ((j&1)*16 + 4*g + r)) & 1u) ? s[j][r] : -1e9f;
        ll += exp2f(sv);
      }
    }
  }
  ll += __shfl_xor(ll, 16);
  ll += __shfl_xor(ll, 32);
  const float rl = 1.f / ll;

  // ---- pass 2: recompute, LDS-transpose, full-line NT attn stores, num, lane-local PV ----
  f4 oacc[2] = {f4z, f4z};
  f4* Sw = S4[wid];
  float* abase = attn + (bh + q0 + wid*16)*TE;
  for(int kt=0; kt<32; ++kt){
    h8 kf[4];
    #pragma unroll
    for(int j=0;j<4;j++) kf[j] = *(const h8*)(Kg + (size_t)(kt*64 + j*16 + c)*32 + g*8);
    f4 s[4];
    #pragma unroll
    for(int j=0;j<4;j++) s[j] = __builtin_amdgcn_mfma_f32_16x16x32_f16(kf[j], qf, f4z, 0, 0, 0);
    const uint2 mw2 = mrow2[kt];
    unsigned int pk[4][2];
    #pragma unroll
    for(int j=0;j<4;j++){
      const unsigned mw = (j>>1) ? mw2.y : mw2.x;
      f4 p;
      #pragma unroll
      for(int r=0;r<4;r++){
        float sv = ((mw >> ((j&1)*16 + 4*g + r)) & 1u) ? s[j][r] : -1e9f;
        p[r] = exp2f(sv) * rl;
      }
      Sw[c*17 + 4*j + g] = p;                       // strip write
      pk[j][0] = packh2(p[0], p[1]);
      pk[j][1] = packh2(p[2], p[3]);
    }
    // PV first (overlaps strip-write latency): mfma(V,P), V-frag one contiguous h8
    #pragma unroll
    for(int kc=0;kc<2;kc++){
      uint4 pu = {pk[2*kc][0], pk[2*kc][1], pk[2*kc+1][0], pk[2*kc+1][1]};
      h8 pf = __builtin_bit_cast(h8, pu);
      #pragma unroll
      for(int du=0;du<2;du++){
        h8 vf = *(const h8*)(Vg + (size_t)(du*16 + c)*TE + kt*64 + kc*32 + g*8);
        oacc[du] = __builtin_amdgcn_mfma_f32_16x16x32_f16(vf, pf, oacc[du], 0, 0, 0);
      }
    }
    // read back transposed: lane l -> rows {u*4+g}, chunk c (4 rows x 256B per store instr)
    f4 v[4];
    #pragma unroll
    for(int u=0;u<4;u++) v[u] = Sw[(u*4+g)*17 + c];
    #pragma unroll
    for(int u=0;u<4;u++)
      __builtin_nontemporal_store(v[u], (f4*)(abase + (size_t)(u*4+g)*TE + kt*64 + c*4));
    f4 a = v[0] + v[1] + v[2] + v[3];
    #pragma unroll
    for(int q=0;q<4;q++){ a[q] += __shfl_xor(a[q], 16); a[q] += __shfl_xor(a[q], 32); }
    if(l < 16){
      float* np = &num_s[kt*64 + c*4];
      atomicAdd(np+0, a[0]); atomicAdd(np+1, a[1]);
      atomicAdd(np+2, a[2]); atomicAdd(np+3, a[3]);
    }
  }

  // O write: [B,E,256] fp16; lane c = q-row, regs = 4 consecutive d
  #pragma unroll
  for(int du=0;du<2;du++){
    uint2 ov;
    ov.x = packh2(oacc[du][0], oacc[du][1]);
    ov.y = packh2(oacc[du][2], oacc[du][3]);
    *(uint2*)&owh[((size_t)b*TE + q0 + qr)*256 + h*32 + du*16 + 4*g] = ov;
  }
  __syncthreads();
  for(int i=t;i<TE;i+=256) atomicAdd(&num[(size_t)b*TE + i], num_s[i]);
}

// ---------------- output projection (MFMA) + residual + transpose ----------------
__global__ __launch_bounds__(256) void k_fc(
    const _Float16* __restrict__ owh, const _Float16* __restrict__ fcT,
    const float* __restrict__ x, float* __restrict__ xout){
  __shared__ float xt[16][260];
  const int t = threadIdx.x;
  const int b = blockIdx.y;
  const int e0 = blockIdx.x * 16;
  for(int i=t;i<4096;i+=256){
    int el = i & 15, dd = i >> 4;
    xt[el][dd] = x[((size_t)(b*TD + dd))*TE + e0 + el];
  }
  const int w = t >> 6, l = t & 63, g = l >> 4, c = l & 15;
  h8 af[8];
  #pragma unroll
  for(int kk=0;kk<8;kk++)
    af[kk] = *(const h8*)(owh + ((size_t)b*TE + e0 + c)*256 + kk*32 + g*8);
  f4 accs[4];
  #pragma unroll
  for(int i=0;i<4;i++){
    const int n0 = w*64 + i*16;
    f4 acc = {0.f,0.f,0.f,0.f};
    #pragma unroll
    for(int kk=0;kk<8;kk++){
      h8 bf = *(const h8*)(fcT + (size_t)(n0 + c)*256 + kk*32 + g*8);
      acc = __builtin_amdgcn_mfma_f32_16x16x32_f16(bf, af[kk], acc, 0, 0, 0);
    }
    accs[i] = acc;
  }
  __syncthreads();
  #pragma unroll
  for(int i=0;i<4;i++){
    const int n0 = w*64 + i*16 + 4*g;
    #pragma unroll
    for(int r=0;r<4;r++) xt[c][n0+r] += accs[i][r];
  }
  __syncthreads();
  for(int i=t;i<4096;i+=256){
    int el = i & 15, dd = i >> 4;
    xout[((size_t)(b*TD + dd))*TE + e0 + el] = xt[el][dd];
  }
}

// ---------------- per-edge final: num / (H * denom) ----------------
__global__ void k_edge(const float* __restrict__ num, const float* __restrict__ denom,
                       float* __restrict__ pe){
  int idx = blockIdx.x*256 + threadIdx.x;
  pe[idx] = num[idx] / (8.f * denom[idx]);
}

extern "C" void kernel_launch(void* const* d_in, const int* in_sizes, int n_in,
                              void* d_out, int out_size, void* d_ws, size_t ws_size,
                              hipStream_t stream){
  const float* x   = (const float*)d_in[0];
  const unsigned int* mraw = (const unsigned int*)d_in[1];
  const float* wqs = (const float*)d_in[2];
  const float* wks = (const float*)d_in[3];
  const float* wvs = (const float*)d_in[4];
  const float* wfc = (const float*)d_in[5];
  const float* gamma = (const float*)d_in[6];
  const float* beta  = (const float*)d_in[7];

  float* xout = (float*)d_out;                               // [B,D,E]
  float* attn = xout + (size_t)TB*TD*TE;                     // [B,H,E,E]
  float* pe   = attn + (size_t)TB*TH*TE*TE;                  // [B,E]

  const size_t SZ = (size_t)TB*TH*TE*32;                     // 4,194,304
  _Float16* qhp = (_Float16*)((char*)d_ws + 256);
  _Float16* khp = qhp + SZ;
  _Float16* vtp = khp + SZ;                                  // V^T [B,H,32,E] slot-permuted
  _Float16* owh = vtp + SZ;                                  // [B,E,256] fp16
  unsigned int* packed = (unsigned int*)(owh + SZ);          // 4 MB
  float* num   = (float*)(packed + (size_t)TB*TE*64);
  float* denom = num + (size_t)TB*TE;
  _Float16* qkvT = (_Float16*)(denom + (size_t)TB*TE);       // [768][256] fp16
  _Float16* fcT  = qkvT + 768*256;                           // [256][256] fp16

  hipMemsetAsync(denom, 0, (size_t)TB*TE*sizeof(float), stream);
  k_wpack<<<1024, 256, 0, stream>>>(wqs, wks, wvs, wfc, qkvT, fcT);
  k_pack<<<TB*TE/4, 256, 0, stream>>>(mraw, packed, num);
  k_denom<<<dim3(TE/256, TE/64, TB), 256, 0, stream>>>(packed, denom);
  k_qkv<<<dim3(TE/16, TB), 256, 0, stream>>>(x, qkvT, gamma, beta, qhp, khp, vtp);
  k_attn<<<TB*TH*TE/64, 256, 0, stream>>>(qhp, khp, vtp, packed, attn, owh, num);
  k_fc<<<dim3(TE/16, TB), 256, 0, stream>>>(owh, fcT, x, xout);
  k_edge<<<TB*TE/256, 256, 0, stream>>>(num, denom, pe);
}

// Round 7
// 403.777 us; speedup vs baseline: 1.1071x; 1.1071x over previous
//
#include <hip/hip_runtime.h>
#include <hip/hip_fp16.h>
#include <math.h>

#define TB 8      // batch
#define TD 256    // d_model
#define TE 2048   // edges (sequence)
#define TH 8      // heads

typedef _Float16 h8 __attribute__((ext_vector_type(8)));
typedef float    f4 __attribute__((ext_vector_type(4)));

static __device__ __forceinline__ unsigned int packh2(float a, float b){
  __half2 h = __floats2half2_rn(a, b);
  return __builtin_bit_cast(unsigned int, h);
}

// ---------------- pack mask rows into bitmask [B*E][64 words]; self-detecting dtype ----------------
__global__ __launch_bounds__(256) void k_pack(const unsigned int* __restrict__ mraw,
                       unsigned int* __restrict__ packed, float* __restrict__ num){
  __shared__ int oks;
  const int t = threadIdx.x;
  if(t == 0) oks = 1;
  __syncthreads();
  int ok = 1;
  for(int i=t; i<4096; i+=256) if(mraw[i] > 1u) ok = 0;
  if(!ok) atomicAnd(&oks, 0);
  __syncthreads();
  const int isInt = oks;

  const int row = blockIdx.x*4 + (t >> 6);
  const int w = t & 63;
  const size_t base = (size_t)row*TE + (size_t)w*32;
  unsigned int bits = 0;
  if(isInt){
    const unsigned int* p = mraw + base;
    #pragma unroll
    for(int j=0;j<32;j++) bits |= (p[j] & 1u) << j;
  } else {
    const unsigned char* p = (const unsigned char*)mraw + base;
    #pragma unroll
    for(int j=0;j<32;j++) bits |= (unsigned int)(p[j] != 0) << j;
  }
  packed[(size_t)row*64 + w] = bits;
  if(blockIdx.x < 64) num[blockIdx.x*256 + t] = 0.f;   // zero per-edge numerator
}

// ---------------- denom[b][k] = sum_q mask[b][q][k] (from packed bits) ----------------
__global__ __launch_bounds__(256) void k_denom(const unsigned int* __restrict__ packed,
                        float* __restrict__ denom){
  const int b = blockIdx.z;
  const int k = blockIdx.x*256 + threadIdx.x;
  const int q0 = blockIdx.y*64;
  const unsigned int* p = packed + ((size_t)b*TE + q0)*64 + (k >> 5);
  const unsigned sh = k & 31;
  int cnt = 0;
  #pragma unroll 8
  for(int q=0;q<64;q++) cnt += (p[(size_t)q*64] >> sh) & 1u;
  atomicAdd(&denom[b*TE + k], (float)cnt);
}

// ---------------- weight transpose to fp16: qkvT [768][256] (Q|K|V cols), fcT [256][256] ----------------
__global__ __launch_bounds__(256) void k_wpack(
    const float* __restrict__ wqs, const float* __restrict__ wks,
    const float* __restrict__ wvs, const float* __restrict__ wfc,
    _Float16* __restrict__ qkvT, _Float16* __restrict__ fcT){
  const int n = blockIdx.x;          // 0..1023
  const int k = threadIdx.x;         // 0..255
  if(n < 256)      qkvT[(size_t)n*256 + k] = (_Float16)wqs[(size_t)k*256 + n];
  else if(n < 512) qkvT[(size_t)n*256 + k] = (_Float16)wks[(size_t)k*256 + (n-256)];
  else if(n < 768) qkvT[(size_t)n*256 + k] = (_Float16)wvs[(size_t)k*256 + (n-512)];
  else             fcT[(size_t)(n-768)*256 + k] = (_Float16)wfc[(size_t)k*256 + (n-768)];
}

// ---------------- transpose + LayerNorm + Q/K/V projections (MFMA) ----------------
// 16 edges/block, 4 waves. Wave w owns N-tiles {4w..4w+3} of each of Q, K, V.
__global__ __launch_bounds__(256) void k_qkv(
    const float* __restrict__ x, const _Float16* __restrict__ qkvT,
    const float* __restrict__ gamma, const float* __restrict__ beta,
    _Float16* __restrict__ qh, _Float16* __restrict__ kh, _Float16* __restrict__ vt){
  __shared__ float xs[16][260];
  __shared__ __align__(16) _Float16 xh[16][264];
  __shared__ __align__(16) _Float16 qn[16][264];
  __shared__ float mu_s[16], rs_s[16];
  const int t = threadIdx.x;
  const int b = blockIdx.y;
  const int e0 = blockIdx.x*16;

  for(int i=t;i<16*256;i+=256){
    int el = i & 15, dd = i >> 4;
    xs[el][dd] = x[((size_t)(b*TD + dd))*TE + e0 + el];
  }
  __syncthreads();
  {
    int row = t >> 4, j = t & 15;
    float s1=0.f, s2=0.f;
    #pragma unroll
    for(int i=0;i<16;i++){ float v = xs[row][j*16+i]; s1 += v; s2 += v*v; }
    #pragma unroll
    for(int off=1; off<16; off<<=1){ s1 += __shfl_xor(s1, off); s2 += __shfl_xor(s2, off); }
    if(j==0){
      float m = s1 * (1.f/256.f);
      float var = s2 * (1.f/256.f) - m*m;
      mu_s[row] = m;
      rs_s[row] = rsqrtf(var + 1e-6f);
    }
  }
  __syncthreads();
  for(int i=t;i<16*256;i+=256){
    int r = i >> 8, dd = i & 255;
    float xv = xs[r][dd];
    xh[r][dd] = (_Float16)xv;
    qn[r][dd] = (_Float16)((xv - mu_s[r]) * rs_s[r] * gamma[dd] + beta[dd]);
  }
  __syncthreads();

  const int w = t >> 6, l = t & 63, g = l >> 4, c = l & 15;
  const f4 f4z = {0.f,0.f,0.f,0.f};
  const float sclq = 0.17677669529663687f * 1.44269504088896f;  // 1/sqrt(DK) * log2(e)
  h8 af[8];

  // ---- Q ----
  #pragma unroll
  for(int kk=0;kk<8;kk++) af[kk] = *(const h8*)&qn[c][kk*32 + g*8];
  #pragma unroll
  for(int i=0;i<4;i++){
    const int n0 = (4*w+i)*16;
    f4 acc = f4z;
    #pragma unroll
    for(int kk=0;kk<8;kk++){
      h8 bf = *(const h8*)(qkvT + (size_t)(n0 + c)*256 + kk*32 + g*8);
      acc = __builtin_amdgcn_mfma_f32_16x16x32_f16(bf, af[kk], acc, 0, 0, 0);
    }
    const int d0 = n0 + 4*g, hh = d0 >> 5, d2 = d0 & 31;
    uint2 ov;
    ov.x = packh2(acc[0]*sclq, acc[1]*sclq);
    ov.y = packh2(acc[2]*sclq, acc[3]*sclq);
    *(uint2*)&qh[((size_t)(b*TH+hh)*TE + e0 + c)*32 + d2] = ov;
  }
  // ---- K ----
  #pragma unroll
  for(int kk=0;kk<8;kk++) af[kk] = *(const h8*)&xh[c][kk*32 + g*8];
  #pragma unroll
  for(int i=0;i<4;i++){
    const int n0 = (4*w+i)*16;
    f4 acc = f4z;
    #pragma unroll
    for(int kk=0;kk<8;kk++){
      h8 bf = *(const h8*)(qkvT + (size_t)(256 + n0 + c)*256 + kk*32 + g*8);
      acc = __builtin_amdgcn_mfma_f32_16x16x32_f16(bf, af[kk], acc, 0, 0, 0);
    }
    const int d0 = n0 + 4*g, hh = d0 >> 5, d2 = d0 & 31;
    uint2 ov;
    ov.x = packh2(acc[0], acc[1]);
    ov.y = packh2(acc[2], acc[3]);
    *(uint2*)&kh[((size_t)(b*TH+hh)*TE + e0 + c)*32 + d2] = ov;
  }
  // ---- V (transposed + slot-permuted; quad-transpose -> 8B packed stores) ----
  // slot layout within each 32-e window: e' = 8*a + 4*jj + q  for edge e0+4a+q
  const int jj = (e0 >> 4) & 1;
  const int p = c & 3, a = c >> 2;
  #pragma unroll
  for(int i=0;i<4;i++){
    const int n0 = (4*w+i)*16;
    f4 acc = f4z;
    #pragma unroll
    for(int kk=0;kk<8;kk++){
      h8 bf = *(const h8*)(qkvT + (size_t)(512 + n0 + c)*256 + kk*32 + g*8);
      acc = __builtin_amdgcn_mfma_f32_16x16x32_f16(bf, af[kk], acc, 0, 0, 0);
    }
    // 4x4 quad transpose: lane p ends with elem q = orig(lane q, elem p)
    f4 n_, fv;
    #pragma unroll
    for(int r=0;r<4;r++){
      float o = __shfl_xor(acc[r^1], 1);
      n_[r] = ((p^r)&1) ? o : acc[r];
    }
    #pragma unroll
    for(int r=0;r<4;r++){
      float o = __shfl_xor(n_[r^2], 2);
      fv[r] = ((p^r)&2) ? o : n_[r];
    }
    const int d = n0 + 4*g + p;
    uint2 ov;
    ov.x = packh2(fv[0], fv[1]);
    ov.y = packh2(fv[2], fv[3]);
    *(uint2*)&vt[((size_t)(b*TH + (d>>5))*32 + (d&31))*TE + (e0 & ~31) + 8*a + 4*jj] = ov;
  }
}

// ---------------- MFMA attention, swapped-operand, LDS-transposed full-line stores ----------------
// 1 block = 64 q-rows of one (b,h). 4 waves x 16 rows. Two passes over K.
// Mask staged once into LDS (coalesced), read via ds_read_b64 broadcast per kt.
__global__ __launch_bounds__(256) void k_attn(
    const _Float16* __restrict__ qh, const _Float16* __restrict__ kh, const _Float16* __restrict__ vt,
    const unsigned int* __restrict__ packed,
    float* __restrict__ attn, _Float16* __restrict__ owh, float* __restrict__ num){
  __shared__ __align__(16) unsigned int mb[64][66];
  __shared__ float num_s[TE];
  __shared__ __align__(16) f4 S4[4][272];            // per-wave strip: 16 rows x 17 f4 (pad)

  const int t = threadIdx.x;
  int bid = blockIdx.x;
  bid = (bid & 7) * 256 + (bid >> 3);                // XCD-aware swizzle (2048 % 8 == 0)
  const int qt = bid & 31;
  const int bhid = bid >> 5;                         // 0..63
  const int h = bhid & 7, b = bhid >> 3;
  const size_t bh = (size_t)bhid * TE;
  const _Float16* Qg = qh + bh*32;
  const _Float16* Kg = kh + bh*32;
  const _Float16* Vg = vt + bh*32;                   // [32][TE], slot-permuted
  const int q0 = qt*64;

  const int wid = t >> 6, l = t & 63, g = l >> 4, c = l & 15;
  const int qr = wid*16 + c;
  const f4 f4z = {0.f, 0.f, 0.f, 0.f};

  for(int i=t;i<TE;i+=256) num_s[i] = 0.f;
  for(int i=t;i<64*64;i+=256){
    int r = i >> 6, w = i & 63;
    mb[r][w] = packed[((size_t)b*TE + q0 + r)*64 + w];
  }
  __syncthreads();

  // Q fragment (B-operand): lane holds Q-row (q0+qr), k-slice g*8 (log2e pre-folded)
  const h8 qf = *(const h8*)(Qg + (size_t)(q0 + qr)*32 + g*8);

  // ---- pass 1: row sums of 2^s (no max-sub; masked -> 2^(-1e9)=0) ----
  float ll = 0.f;
  for(int kt=0; kt<32; ++kt){
    h8 kf[4];
    #pragma unroll
    for(int j=0;j<4;j++) kf[j] = *(const h8*)(Kg + (size_t)(kt*64 + j*16 + c)*32 + g*8);
    f4 s[4];
    #pragma unroll
    for(int j=0;j<4;j++) s[j] = __builtin_amdgcn_mfma_f32_16x16x32_f16(kf[j], qf, f4z, 0, 0, 0);
    const uint2 mw2 = *(const uint2*)&mb[qr][2*kt];
    #pragma unroll
    for(int j=0;j<4;j++){
      const unsigned mw = (j>>1) ? mw2.y : mw2.x;
      #pragma unroll
      for(int r=0;r<4;r++){
        float sv = ((mw >> ((j&1)*16 + 4*g + r)) & 1u) ? s[j][r] : -1e9f;
        ll += exp2f(sv);
      }
    }
  }
  ll += __shfl_xor(ll, 16);
  ll += __shfl_xor(ll, 32);
  const float rl = 1.f / ll;

  // ---- pass 2: recompute, LDS-transpose, full-line NT attn stores, num, lane-local PV ----
  f4 oacc[2] = {f4z, f4z};
  f4* Sw = S4[wid];
  float* abase = attn + (bh + q0 + wid*16)*TE;
  for(int kt=0; kt<32; ++kt){
    h8 kf[4];
    #pragma unroll
    for(int j=0;j<4;j++) kf[j] = *(const h8*)(Kg + (size_t)(kt*64 + j*16 + c)*32 + g*8);
    f4 s[4];
    #pragma unroll
    for(int j=0;j<4;j++) s[j] = __builtin_amdgcn_mfma_f32_16x16x32_f16(kf[j], qf, f4z, 0, 0, 0);
    const uint2 mw2 = *(const uint2*)&mb[qr][2*kt];
    unsigned int pk[4][2];
    #pragma unroll
    for(int j=0;j<4;j++){
      const unsigned mw = (j>>1) ? mw2.y : mw2.x;
      f4 p;
      #pragma unroll
      for(int r=0;r<4;r++){
        float sv = ((mw >> ((j&1)*16 + 4*g + r)) & 1u) ? s[j][r] : -1e9f;
        p[r] = exp2f(sv) * rl;
      }
      Sw[c*17 + 4*j + g] = p;                       // strip write
      pk[j][0] = packh2(p[0], p[1]);
      pk[j][1] = packh2(p[2], p[3]);
    }
    // PV first (overlaps strip-write latency): mfma(V,P), V-frag one contiguous h8
    #pragma unroll
    for(int kc=0;kc<2;kc++){
      uint4 pu = {pk[2*kc][0], pk[2*kc][1], pk[2*kc+1][0], pk[2*kc+1][1]};
      h8 pf = __builtin_bit_cast(h8, pu);
      #pragma unroll
      for(int du=0;du<2;du++){
        h8 vf = *(const h8*)(Vg + (size_t)(du*16 + c)*TE + kt*64 + kc*32 + g*8);
        oacc[du] = __builtin_amdgcn_mfma_f32_16x16x32_f16(vf, pf, oacc[du], 0, 0, 0);
      }
    }
    // read back transposed: lane l -> rows {u*4+g}, chunk c (4 rows x 256B per store instr)
    f4 v[4];
    #pragma unroll
    for(int u=0;u<4;u++) v[u] = Sw[(u*4+g)*17 + c];
    #pragma unroll
    for(int u=0;u<4;u++)
      __builtin_nontemporal_store(v[u], (f4*)(abase + (size_t)(u*4+g)*TE + kt*64 + c*4));
    f4 a = v[0] + v[1] + v[2] + v[3];
    #pragma unroll
    for(int q=0;q<4;q++){ a[q] += __shfl_xor(a[q], 16); a[q] += __shfl_xor(a[q], 32); }
    if(l < 16){
      float* np = &num_s[kt*64 + c*4];
      atomicAdd(np+0, a[0]); atomicAdd(np+1, a[1]);
      atomicAdd(np+2, a[2]); atomicAdd(np+3, a[3]);
    }
  }

  // O write: [B,E,256] fp16; lane c = q-row, regs = 4 consecutive d
  #pragma unroll
  for(int du=0;du<2;du++){
    uint2 ov;
    ov.x = packh2(oacc[du][0], oacc[du][1]);
    ov.y = packh2(oacc[du][2], oacc[du][3]);
    *(uint2*)&owh[((size_t)b*TE + q0 + qr)*256 + h*32 + du*16 + 4*g] = ov;
  }
  __syncthreads();
  for(int i=t;i<TE;i+=256) atomicAdd(&num[(size_t)b*TE + i], num_s[i]);
}

// ---------------- output projection (MFMA) + residual + transpose ----------------
__global__ __launch_bounds__(256) void k_fc(
    const _Float16* __restrict__ owh, const _Float16* __restrict__ fcT,
    const float* __restrict__ x, float* __restrict__ xout){
  __shared__ float xt[16][260];
  const int t = threadIdx.x;
  const int b = blockIdx.y;
  const int e0 = blockIdx.x * 16;
  for(int i=t;i<4096;i+=256){
    int el = i & 15, dd = i >> 4;
    xt[el][dd] = x[((size_t)(b*TD + dd))*TE + e0 + el];
  }
  const int w = t >> 6, l = t & 63, g = l >> 4, c = l & 15;
  h8 af[8];
  #pragma unroll
  for(int kk=0;kk<8;kk++)
    af[kk] = *(const h8*)(owh + ((size_t)b*TE + e0 + c)*256 + kk*32 + g*8);
  f4 accs[4];
  #pragma unroll
  for(int i=0;i<4;i++){
    const int n0 = w*64 + i*16;
    f4 acc = {0.f,0.f,0.f,0.f};
    #pragma unroll
    for(int kk=0;kk<8;kk++){
      h8 bf = *(const h8*)(fcT + (size_t)(n0 + c)*256 + kk*32 + g*8);
      acc = __builtin_amdgcn_mfma_f32_16x16x32_f16(bf, af[kk], acc, 0, 0, 0);
    }
    accs[i] = acc;
  }
  __syncthreads();
  #pragma unroll
  for(int i=0;i<4;i++){
    const int n0 = w*64 + i*16 + 4*g;
    #pragma unroll
    for(int r=0;r<4;r++) xt[c][n0+r] += accs[i][r];
  }
  __syncthreads();
  for(int i=t;i<4096;i+=256){
    int el = i & 15, dd = i >> 4;
    xout[((size_t)(b*TD + dd))*TE + e0 + el] = xt[el][dd];
  }
}

// ---------------- per-edge final: num / (H * denom) ----------------
__global__ void k_edge(const float* __restrict__ num, const float* __restrict__ denom,
                       float* __restrict__ pe){
  int idx = blockIdx.x*256 + threadIdx.x;
  pe[idx] = num[idx] / (8.f * denom[idx]);
}

extern "C" void kernel_launch(void* const* d_in, const int* in_sizes, int n_in,
                              void* d_out, int out_size, void* d_ws, size_t ws_size,
                              hipStream_t stream){
  const float* x   = (const float*)d_in[0];
  const unsigned int* mraw = (const unsigned int*)d_in[1];
  const float* wqs = (const float*)d_in[2];
  const float* wks = (const float*)d_in[3];
  const float* wvs = (const float*)d_in[4];
  const float* wfc = (const float*)d_in[5];
  const float* gamma = (const float*)d_in[6];
  const float* beta  = (const float*)d_in[7];

  float* xout = (float*)d_out;                               // [B,D,E]
  float* attn = xout + (size_t)TB*TD*TE;                     // [B,H,E,E]
  float* pe   = attn + (size_t)TB*TH*TE*TE;                  // [B,E]

  const size_t SZ = (size_t)TB*TH*TE*32;                     // 4,194,304
  _Float16* qhp = (_Float16*)((char*)d_ws + 256);
  _Float16* khp = qhp + SZ;
  _Float16* vtp = khp + SZ;                                  // V^T [B,H,32,E] slot-permuted
  _Float16* owh = vtp + SZ;                                  // [B,E,256] fp16
  unsigned int* packed = (unsigned int*)(owh + SZ);          // 4 MB
  float* num   = (float*)(packed + (size_t)TB*TE*64);
  float* denom = num + (size_t)TB*TE;
  _Float16* qkvT = (_Float16*)(denom + (size_t)TB*TE);       // [768][256] fp16
  _Float16* fcT  = qkvT + 768*256;                           // [256][256] fp16

  hipMemsetAsync(denom, 0, (size_t)TB*TE*sizeof(float), stream);
  k_wpack<<<1024, 256, 0, stream>>>(wqs, wks, wvs, wfc, qkvT, fcT);
  k_pack<<<TB*TE/4, 256, 0, stream>>>(mraw, packed, num);
  k_denom<<<dim3(TE/256, TE/64, TB), 256, 0, stream>>>(packed, denom);
  k_qkv<<<dim3(TE/16, TB), 256, 0, stream>>>(x, qkvT, gamma, beta, qhp, khp, vtp);
  k_attn<<<TB*TH*TE/64, 256, 0, stream>>>(qhp, khp, vtp, packed, attn, owh, num);
  k_fc<<<dim3(TE/16, TB), 256, 0, stream>>>(owh, fcT, x, xout);
  k_edge<<<TB*TE/256, 256, 0, stream>>>(num, denom, pe);
}